// Round 9
// baseline (395.480 us; speedup 1.0000x reference)
//
#include <hip/hip_runtime.h>

typedef unsigned short u16;
typedef unsigned int u32;
typedef short vbf16x8 __attribute__((ext_vector_type(8)));   // 8 bf16 as shorts (4 VGPR)
typedef float vf32x4 __attribute__((ext_vector_type(4)));
typedef int vi32x4 __attribute__((ext_vector_type(4)));

#define MFMA16(a,b,c) __builtin_amdgcn_mfma_f32_16x16x32_bf16((a),(b),(c),0,0,0)

__device__ __forceinline__ u16 f2bf(float f) {
  union { float f; unsigned u; } c; c.f = f;
  unsigned r = c.u + 0x7fffu + ((c.u >> 16) & 1u);
  return (u16)(r >> 16);
}
__device__ __forceinline__ float bf2f(u16 h) {
  union { unsigned u; float f; } c; c.u = ((u32)h) << 16; return c.f;
}

// ---------------- prep: weight transposes (bf16) ----------------
__global__ __launch_bounds__(256) void k_prep_w(
    const float* __restrict__ w1, const float* __restrict__ w2,
    const float* __restrict__ u1, const float* __restrict__ u2,
    u16* __restrict__ wcatT, u16* __restrict__ w2T,
    u16* __restrict__ u1bT, u16* __restrict__ u2T) {
  int id = blockIdx.x * 256 + threadIdx.x;
  if (id < 49152) {
    int n = id >> 7, k = id & 127;
    float v;
    if (n < 128) v = w1[(128 + k) * 128 + n];
    else if (n < 256) v = w1[k * 128 + (n - 128)];
    else v = u1[k * 128 + (n - 256)];
    wcatT[id] = f2bf(v);
  } else {
    int id2 = id - 49152;
    int m = id2 >> 14, r = id2 & 16383;
    int n = r >> 7, k = r & 127;
    if (m == 0) w2T[r] = f2bf(w2[k * 128 + n]);
    else if (m == 1) u1bT[r] = f2bf(u1[(128 + k) * 128 + n]);
    else u2T[r] = f2bf(u2[k * 128 + n]);
  }
}

// ---------------- norms: xnf (f32), xbf (raw bf16), xnthl (hi/lo bf16, MFMA-granule-tiled) ---------
// xnthl: per 16-row group, 4096 u16: [hi granules 2048][lo granules 2048];
// granule (row j, ks, lg) at hl*2048 + ks*512 + lg*128 + (j&15)*8. lo = bf16(n - f32(bf16(n))).
__global__ __launch_bounds__(256) void k_norm(
    const float* __restrict__ x, float* __restrict__ xnf,
    u16* __restrict__ xnthl, u16* __restrict__ xbf, int* __restrict__ cnt) {
  __shared__ u16 bh[4][128], bl[4][128];
  int tid = threadIdx.x;
  int gid = blockIdx.x * 256 + tid;
  if (gid < 16384) cnt[gid] = 0;
  int lane = tid & 63, w = tid >> 6;
  int row = blockIdx.x * 4 + w;
  size_t b = (size_t)row * 128;
  float v0 = x[b + lane], v1 = x[b + 64 + lane];
  float ss = v0 * v0 + v1 * v1;
  #pragma unroll
  for (int m = 32; m > 0; m >>= 1) ss += __shfl_xor(ss, m);
  float d = fmaxf(sqrtf(ss), 1e-8f);
  float n0 = v0 / d, n1 = v1 / d;
  xnf[b + lane] = n0; xnf[b + 64 + lane] = n1;
  xbf[b + lane] = f2bf(v0); xbf[b + 64 + lane] = f2bf(v1);
  u16 h0 = f2bf(n0), h1 = f2bf(n1);
  bh[w][lane] = h0; bh[w][64 + lane] = h1;
  bl[w][lane] = f2bf(n0 - bf2f(h0)); bl[w][64 + lane] = f2bf(n1 - bf2f(h1));
  __syncthreads();
  if (tid < 64) {
    int r = tid >> 4, g = tid & 15;
    int grow = blockIdx.x * 4 + r;
    size_t base = (size_t)(grow >> 4) * 4096 + (g >> 2) * 512 + (g & 3) * 128 + (grow & 15) * 8;
    *(vi32x4*)&xnthl[base] = *(const vi32x4*)&bh[r][g * 8];
    *(vi32x4*)&xnthl[base + 2048] = *(const vi32x4*)&bl[r][g * 8];
  }
}

// ---------------- sampling pass: per-(row,seg-stream) top-2 VALUES (hi*hi sims) --------------------
// Block: 256 rows (4 waves x 64 rows) x one 1024-col segment. 3 VALU/value (was 8 with keys).
__global__ __launch_bounds__(256, 2) void k_sim1(
    const u16* __restrict__ xnthl, float* __restrict__ sampV) {
  const int tid = threadIdx.x, lane = tid & 63, w = tid >> 6;
  const int lr = lane & 15, lg = lane >> 4;
  const int seg = blockIdx.x & 15, rbk = blockIdx.x >> 4;
  const int rowbase = rbk * 256 + w * 64;

  vbf16x8 af[4][4];
  #pragma unroll
  for (int a = 0; a < 4; ++a) {
    const u16* tp = xnthl + (size_t)((rowbase >> 4) + a) * 4096;
    #pragma unroll
    for (int ks = 0; ks < 4; ++ks)
      af[a][ks] = *(const vbf16x8*)(tp + ks * 512 + lg * 128 + lr * 8);
  }

  float m1[4][4], m2[4][4];
  #pragma unroll
  for (int a = 0; a < 4; ++a)
    #pragma unroll
    for (int r = 0; r < 4; ++r) { m1[a][r] = -1e30f; m2[a][r] = -1e30f; }

  const u16* segp = xnthl + (size_t)(seg * 64) * 4096;
  vbf16x8 bc[4], bn[4];
  #pragma unroll
  for (int ks = 0; ks < 4; ++ks) bc[ks] = *(const vbf16x8*)(segp + ks * 512 + lane * 8);

#define S1STEP(B) { \
  _Pragma("unroll") \
  for (int a = 0; a < 4; ++a) { \
    vf32x4 acc = {0.f, 0.f, 0.f, 0.f}; \
    _Pragma("unroll") \
    for (int ks = 0; ks < 4; ++ks) acc = MFMA16(af[a][ks], (B)[ks], acc); \
    _Pragma("unroll") \
    for (int r = 0; r < 4; ++r) { \
      float v = acc[r]; \
      m2[a][r] = fmaxf(m2[a][r], fminf(m1[a][r], v)); \
      m1[a][r] = fmaxf(m1[a][r], v); \
    } } }

  #pragma unroll 1
  for (int ti = 0; ti < 32; ++ti) {
    { const u16* tp1 = segp + (size_t)(2 * ti + 1) * 4096;
      #pragma unroll
      for (int ks = 0; ks < 4; ++ks) bn[ks] = *(const vbf16x8*)(tp1 + ks * 512 + lane * 8); }
    S1STEP(bc);
    { int nt = (ti < 31) ? (2 * ti + 2) : 63;
      const u16* tp2 = segp + (size_t)nt * 4096;
      #pragma unroll
      for (int ks = 0; ks < 4; ++ks) bc[ks] = *(const vbf16x8*)(tp2 + ks * 512 + lane * 8); }
    S1STEP(bn);
  }

  // dump 32 samples per (row, seg): sampV[row*512 + seg*32 + {lr, 16+lr}]
  #pragma unroll
  for (int a = 0; a < 4; ++a)
    #pragma unroll
    for (int r = 0; r < 4; ++r) {
      int row = rowbase + a * 16 + lg * 4 + r;
      float* dp = sampV + (size_t)row * 512 + seg * 32;
      dp[lr] = m1[a][r]; dp[16 + lr] = m2[a][r];
    }
}

// ---------------- theta: 28th-largest of 512-sample union, minus 8-sigma hi/lo margin --------------
// sample-28th <= true bf16-28th (subset order stat); -2e-3 covers |sim_hl - sim_bf16| (sigma~2.4e-4)
// so capture (on hl sims) provably includes bf16-top-28 >= fp32-top-20 (rank-8 margin, rounds 1-6).
__global__ __launch_bounds__(256) void k_theta(
    const float* __restrict__ sampV, float* __restrict__ thbuf) {
  const int lane = threadIdx.x & 63, w = threadIdx.x >> 6;
  const int row = blockIdx.x * 4 + w;
  const float* sp = sampV + (size_t)row * 512;
  float v[8];
  #pragma unroll
  for (int q = 0; q < 8; ++q) v[q] = sp[q * 64 + lane];
  float g = -1e30f;
  #pragma unroll 1
  for (int t = 0; t < 28; ++t) {
    float loc = v[0];
    #pragma unroll
    for (int q = 1; q < 8; ++q) loc = fmaxf(loc, v[q]);
    g = loc;
    #pragma unroll
    for (int mm = 1; mm < 64; mm <<= 1) g = fmaxf(g, __shfl_xor(g, mm));
    #pragma unroll
    for (int q = 0; q < 8; ++q) v[q] = (v[q] == g) ? -1e30f : v[q];
  }
  if (lane == 0) thbuf[row] = g - 2e-3f;
}

// ---------------- exact-sim pass: 3-MFMA hi/lo (err ~2e-6 vs fp32), capture (v,col) >= theta -------
// No gather in select anymore: values captured here ARE the rescored sims.
__global__ __launch_bounds__(256, 2) void k_sim2(
    const u16* __restrict__ xnthl, const float* __restrict__ thbuf,
    float* __restrict__ candV, int* __restrict__ candI, int* __restrict__ cnt) {
  const int tid = threadIdx.x, lane = tid & 63, w = tid >> 6;
  const int lr = lane & 15, lg = lane >> 4;
  const int seg = blockIdx.x & 15, rbk = blockIdx.x >> 4;
  const int rowbase = rbk * 256 + w * 64;

  vbf16x8 ah[4][4], al[4][4];
  #pragma unroll
  for (int a = 0; a < 4; ++a) {
    const u16* tp = xnthl + (size_t)((rowbase >> 4) + a) * 4096;
    #pragma unroll
    for (int ks = 0; ks < 4; ++ks) {
      ah[a][ks] = *(const vbf16x8*)(tp + ks * 512 + lg * 128 + lr * 8);
      al[a][ks] = *(const vbf16x8*)(tp + 2048 + ks * 512 + lg * 128 + lr * 8);
    }
  }
  float th[4][4];
  #pragma unroll
  for (int a = 0; a < 4; ++a)
    #pragma unroll
    for (int r = 0; r < 4; ++r) th[a][r] = thbuf[rowbase + a * 16 + lg * 4 + r];

  const u16* segp = xnthl + (size_t)(seg * 64) * 4096;
  vbf16x8 bch[4], bcl[4], bnh[4], bnl[4];
  #pragma unroll
  for (int ks = 0; ks < 4; ++ks) {
    bch[ks] = *(const vbf16x8*)(segp + ks * 512 + lane * 8);
    bcl[ks] = *(const vbf16x8*)(segp + 2048 + ks * 512 + lane * 8);
  }

#define S2STEP(BH, BL, COLB) { \
  _Pragma("unroll") \
  for (int a = 0; a < 4; ++a) { \
    vf32x4 acc = {0.f, 0.f, 0.f, 0.f}; \
    _Pragma("unroll") \
    for (int ks = 0; ks < 4; ++ks) { \
      acc = MFMA16(al[a][ks], (BH)[ks], acc); \
      acc = MFMA16(ah[a][ks], (BL)[ks], acc); \
      acc = MFMA16(ah[a][ks], (BH)[ks], acc); \
    } \
    _Pragma("unroll") \
    for (int r = 0; r < 4; ++r) { \
      float v = acc[r]; \
      if (v >= th[a][r]) { \
        int row = rowbase + a * 16 + lg * 4 + r; \
        int s = atomicAdd(&cnt[row], 1); \
        if (s < 96) { candV[(size_t)row * 96 + s] = v; candI[(size_t)row * 96 + s] = (COLB) + lr; } \
      } } } }

  const int colseg = seg * 1024;
  #pragma unroll 1
  for (int ti = 0; ti < 32; ++ti) {
    { const u16* tp1 = segp + (size_t)(2 * ti + 1) * 4096;
      #pragma unroll
      for (int ks = 0; ks < 4; ++ks) {
        bnh[ks] = *(const vbf16x8*)(tp1 + ks * 512 + lane * 8);
        bnl[ks] = *(const vbf16x8*)(tp1 + 2048 + ks * 512 + lane * 8);
      } }
    S2STEP(bch, bcl, colseg + (2 * ti) * 16);
    { int nt = (ti < 31) ? (2 * ti + 2) : 63;
      const u16* tp2 = segp + (size_t)nt * 4096;
      #pragma unroll
      for (int ks = 0; ks < 4; ++ks) {
        bch[ks] = *(const vbf16x8*)(tp2 + ks * 512 + lane * 8);
        bcl[ks] = *(const vbf16x8*)(tp2 + 2048 + ks * 512 + lane * 8);
      } }
    S2STEP(bnh, bnl, colseg + (2 * ti + 1) * 16);
  }
}

// ---------------- select: rank-count exact-valued candidates; rare hysteresis rescore --------------
// Wave per row; values already ~fp32-exact (2e-6). Items within EPS of the 20th value get an exact
// fp32 gather-rescore (expected <1 beyond the 20th itself -> nearly always skipped).
__global__ __launch_bounds__(256) void k_select(
    const float* __restrict__ xnf,
    const float* __restrict__ candV, const int* __restrict__ candI, const int* __restrict__ cnt,
    float* __restrict__ topV, int* __restrict__ topI) {
  __shared__ float svals[4][96];
  __shared__ int   sidx[4][96];
  const int tid = threadIdx.x, lane = tid & 63, w = tid >> 6;
  const int i = blockIdx.x * 4 + w;
  int c = cnt[i]; if (c > 96) c = 96;
  float v0 = -1e30f, v1 = -1e30f; int i0 = 0x7fffffff, i1 = 0x7fffffff;
  if (lane < c) { v0 = candV[(size_t)i * 96 + lane]; i0 = candI[(size_t)i * 96 + lane]; }
  if (64 + lane < c) { v1 = candV[(size_t)i * 96 + 64 + lane]; i1 = candI[(size_t)i * 96 + 64 + lane]; }
  if (lane < c) { svals[w][lane] = v0; sidx[w][lane] = i0; }
  if (64 + lane < c) { svals[w][64 + lane] = v1; sidx[w][64 + lane] = i1; }
  // per-wave LDS region: wave-internal ordering via lgkmcnt, no barrier needed
  int r0 = 0, r1 = 0;
  #pragma unroll 1
  for (int s = 0; s < c; ++s) {
    float vs = svals[w][s]; int is = sidx[w][s];
    r0 += (vs > v0 || (vs == v0 && is < i0)) ? 1 : 0;
    r1 += (vs > v1 || (vs == v1 && is < i1)) ? 1 : 0;
  }
  bool ok0 = lane < c, ok1 = 64 + lane < c;
  bool win0 = ok0 && r0 < 20, win1 = ok1 && r1 < 20;
  // s20 = min winner value
  float mn = 1e30f;
  if (win0) mn = v0;
  if (win1) mn = fminf(mn, v1);
  #pragma unroll
  for (int m = 1; m < 64; m <<= 1) mn = fminf(mn, __shfl_xor(mn, m));
  const float EPS = 2e-5f;
  bool wd0 = ok0 && fabsf(v0 - mn) <= EPS, wd1 = ok1 && fabsf(v1 - mn) <= EPS;
  int nW = __popcll(__ballot(wd0)) + __popcll(__ballot(wd1));
  if (nW >= 2) { // ambiguity window: exact fp32 rescore of window items (rare)
    float xa = xnf[(size_t)i * 128 + lane], xb = xnf[(size_t)i * 128 + 64 + lane];
    unsigned long long mb = __ballot(wd0);
    while (mb) {
      int bsl = __ffsll((long long)mb) - 1; mb &= mb - 1ull;
      int j = __shfl(i0, bsl);
      float p = xa * xnf[(size_t)j * 128 + lane] + xb * xnf[(size_t)j * 128 + 64 + lane];
      #pragma unroll
      for (int m = 1; m < 64; m <<= 1) p += __shfl_xor(p, m);
      if (lane == bsl) v0 = p;
    }
    mb = __ballot(wd1);
    while (mb) {
      int bsl = __ffsll((long long)mb) - 1; mb &= mb - 1ull;
      int j = __shfl(i1, bsl);
      float p = xa * xnf[(size_t)j * 128 + lane] + xb * xnf[(size_t)j * 128 + 64 + lane];
      #pragma unroll
      for (int m = 1; m < 64; m <<= 1) p += __shfl_xor(p, m);
      if (lane == bsl) v1 = p;
    }
    if (lane < c) svals[w][lane] = v0;
    if (64 + lane < c) svals[w][64 + lane] = v1;
    r0 = 0; r1 = 0;
    #pragma unroll 1
    for (int s = 0; s < c; ++s) {
      float vs = svals[w][s]; int is = sidx[w][s];
      r0 += (vs > v0 || (vs == v0 && is < i0)) ? 1 : 0;
      r1 += (vs > v1 || (vs == v1 && is < i1)) ? 1 : 0;
    }
    win0 = ok0 && r0 < 20; win1 = ok1 && r1 < 20;
  }
  unsigned long long b0 = __ballot(win0);
  if (win0) {
    int pos = __popcll(b0 & ((1ull << lane) - 1ull));
    topV[(size_t)i * 20 + pos] = v0; topI[(size_t)i * 20 + pos] = i0;
  }
  int base1 = __popcll(b0);
  unsigned long long b1 = __ballot(win1);
  if (win1) {
    int pos = base1 + __popcll(b1 & ((1ull << lane) - 1ull));
    topV[(size_t)i * 20 + pos] = v1; topI[(size_t)i * 20 + pos] = i1;
  }
}

// ---------------- precompute U = x@w1[128:], T = x@w1[:128], V = x@uw1[:128] ----------------
__global__ __launch_bounds__(256) void k_pre(
    const u16* __restrict__ xbf, const u16* __restrict__ wcatT,
    float* __restrict__ U, float* __restrict__ T, float* __restrict__ V) {
  const int tid = threadIdx.x, lane = tid & 63, w = tid >> 6;
  const int lr = lane & 15, lg = lane >> 4;
  const int rowbase = blockIdx.x * 64, cb = blockIdx.y;
  const int a = w >> 1, b = w & 1;
  vbf16x8 af[2][4];
  #pragma unroll
  for (int ar = 0; ar < 2; ++ar) {
    const u16* rp = xbf + (size_t)(rowbase + (a * 2 + ar) * 16 + lr) * 128;
    #pragma unroll
    for (int ks = 0; ks < 4; ++ks) af[ar][ks] = *(const vbf16x8*)(rp + ks * 32 + lg * 8);
  }
  vf32x4 z = {0.f, 0.f, 0.f, 0.f};
  vf32x4 acc[2][2] = {{z, z}, {z, z}};
  #pragma unroll
  for (int ks = 0; ks < 4; ++ks) {
    vbf16x8 bf[2];
    #pragma unroll
    for (int cbl = 0; cbl < 2; ++cbl) {
      int gcol = cb * 64 + (b * 2 + cbl) * 16 + lr;
      bf[cbl] = *(const vbf16x8*)(wcatT + (size_t)gcol * 128 + ks * 32 + lg * 8);
    }
    #pragma unroll
    for (int ar = 0; ar < 2; ++ar)
      #pragma unroll
      for (int cbl = 0; cbl < 2; ++cbl)
        acc[ar][cbl] = MFMA16(af[ar][ks], bf[cbl], acc[ar][cbl]);
  }
  #pragma unroll
  for (int ar = 0; ar < 2; ++ar)
    #pragma unroll
    for (int cbl = 0; cbl < 2; ++cbl) {
      int gcol = cb * 64 + (b * 2 + cbl) * 16 + lr;
      #pragma unroll
      for (int r = 0; r < 4; ++r) {
        int grow = rowbase + (a * 2 + ar) * 16 + lg * 4 + r;
        float vv = acc[ar][cbl][r];
        if (gcol < 128)      U[(size_t)grow * 128 + gcol] = vv;
        else if (gcol < 256) T[(size_t)grow * 128 + (gcol - 128)] = vv;
        else                 V[(size_t)grow * 128 + (gcol - 256)] = vv;
      }
    }
}

// ---------------- fused: softmax, G = sum_e s_e*relu(T_i+U_j+b1), h_agg, update MLP ----------------
__global__ __launch_bounds__(256) void k_msg_upd(
    const float* __restrict__ x,
    const float* __restrict__ Uarr, const float* __restrict__ Tarr, const float* __restrict__ Varr,
    const float* __restrict__ topV, const int* __restrict__ topI,
    const float* __restrict__ b1, const float* __restrict__ b2,
    const float* __restrict__ ub1, const float* __restrict__ ub2,
    const u16* __restrict__ w2T, const u16* __restrict__ u1bT, const u16* __restrict__ u2T,
    float* __restrict__ out) {
  __shared__ float wsm[32 * 20];
  __shared__ int   ism[32 * 20];
  __shared__ u16   Gbf[32 * 136];
  __shared__ u16   Hbf[32 * 136];
  const int tid = threadIdx.x, lane = tid & 63, w = tid >> 6;
  const int lr = lane & 15, lg = lane >> 4;
  const int base = blockIdx.x * 32;

  if (tid < 32) { // softmax over top-20 sims (order-independent)
    int i = base + tid;
    float vv[20]; float mx = -1e30f;
    #pragma unroll
    for (int e = 0; e < 20; ++e) { vv[e] = topV[(size_t)i * 20 + e]; mx = fmaxf(mx, vv[e]); }
    float s = 0.f;
    #pragma unroll
    for (int e = 0; e < 20; ++e) { vv[e] = __expf(vv[e] - mx); s += vv[e]; }
    float inv = 1.f / s;
    #pragma unroll
    for (int e = 0; e < 20; ++e) {
      wsm[tid * 20 + e] = vv[e] * inv;
      ism[tid * 20 + e] = topI[(size_t)i * 20 + e];
    }
  }
  __syncthreads();

  { // G step: 8 threads per row, 16 channels each
    int r = tid >> 3, q = tid & 7, ch0 = q * 16;
    int i = base + r;
    vf32x4 z = {0.f, 0.f, 0.f, 0.f};
    vf32x4 tr[4], br[4], acc[4];
    #pragma unroll
    for (int c = 0; c < 4; ++c) {
      tr[c] = *(const vf32x4*)&Tarr[(size_t)i * 128 + ch0 + c * 4];
      br[c] = *(const vf32x4*)&b1[ch0 + c * 4];
      acc[c] = z;
    }
    #pragma unroll 1
    for (int e = 0; e < 20; ++e) {
      int j = ism[r * 20 + e]; float s = wsm[r * 20 + e];
      const vf32x4* up = (const vf32x4*)&Uarr[(size_t)j * 128 + ch0];
      #pragma unroll
      for (int c = 0; c < 4; ++c) {
        vf32x4 u = up[c];
        #pragma unroll
        for (int zz = 0; zz < 4; ++zz) {
          float p = tr[c][zz] + u[zz] + br[c][zz];
          acc[c][zz] += s * fmaxf(p, 0.f);
        }
      }
    }
    #pragma unroll
    for (int c = 0; c < 4; ++c)
      #pragma unroll
      for (int zz = 0; zz < 4; ++zz)
        Gbf[r * 136 + ch0 + c * 4 + zz] = f2bf(acc[c][zz]);
  }
  __syncthreads();

  const int rt = w >> 1, cg = w & 1;
  vf32x4 z4 = {0.f, 0.f, 0.f, 0.f};
  { // GEMM1: h_agg = G @ w2 + b2 -> Hbf
    vf32x4 acc[4] = {z4, z4, z4, z4};
    #pragma unroll
    for (int ks = 0; ks < 4; ++ks) {
      vbf16x8 a = *(const vbf16x8*)&Gbf[(rt * 16 + lr) * 136 + ks * 32 + lg * 8];
      #pragma unroll
      for (int c = 0; c < 4; ++c) {
        int col = (cg * 4 + c) * 16 + lr;
        vbf16x8 bb = *(const vbf16x8*)(w2T + (size_t)col * 128 + ks * 32 + lg * 8);
        acc[c] = MFMA16(a, bb, acc[c]);
      }
    }
    #pragma unroll
    for (int c = 0; c < 4; ++c) {
      int col = (cg * 4 + c) * 16 + lr;
      float bias = b2[col];
      #pragma unroll
      for (int r = 0; r < 4; ++r) {
        int row = rt * 16 + lg * 4 + r;
        Hbf[row * 136 + col] = f2bf(acc[c][r] + bias);
      }
    }
  }
  __syncthreads();
  { // GEMM2: pre = h_agg @ uw1[128:] + V_i + ub1, relu -> Gbf (reused as P)
    vf32x4 acc[4] = {z4, z4, z4, z4};
    #pragma unroll
    for (int ks = 0; ks < 4; ++ks) {
      vbf16x8 a = *(const vbf16x8*)&Hbf[(rt * 16 + lr) * 136 + ks * 32 + lg * 8];
      #pragma unroll
      for (int c = 0; c < 4; ++c) {
        int col = (cg * 4 + c) * 16 + lr;
        vbf16x8 bb = *(const vbf16x8*)(u1bT + (size_t)col * 128 + ks * 32 + lg * 8);
        acc[c] = MFMA16(a, bb, acc[c]);
      }
    }
    #pragma unroll
    for (int c = 0; c < 4; ++c) {
      int col = (cg * 4 + c) * 16 + lr;
      float bias = ub1[col];
      #pragma unroll
      for (int r = 0; r < 4; ++r) {
        int row = rt * 16 + lg * 4 + r;
        float vv = acc[c][r] + Varr[(size_t)(base + row) * 128 + col] + bias;
        Gbf[row * 136 + col] = f2bf(fmaxf(vv, 0.f));
      }
    }
  }
  __syncthreads();
  { // GEMM3: out = x + P @ uw2 + ub2
    vf32x4 acc[4] = {z4, z4, z4, z4};
    #pragma unroll
    for (int ks = 0; ks < 4; ++ks) {
      vbf16x8 a = *(const vbf16x8*)&Gbf[(rt * 16 + lr) * 136 + ks * 32 + lg * 8];
      #pragma unroll
      for (int c = 0; c < 4; ++c) {
        int col = (cg * 4 + c) * 16 + lr;
        vbf16x8 bb = *(const vbf16x8*)(u2T + (size_t)col * 128 + ks * 32 + lg * 8);
        acc[c] = MFMA16(a, bb, acc[c]);
      }
    }
    #pragma unroll
    for (int c = 0; c < 4; ++c) {
      int col = (cg * 4 + c) * 16 + lr;
      float bias = ub2[col];
      #pragma unroll
      for (int r = 0; r < 4; ++r) {
        int row = rt * 16 + lg * 4 + r;
        size_t o = (size_t)(base + row) * 128 + col;
        out[o] = x[o] + acc[c][r] + bias;
      }
    }
  }
}

extern "C" void kernel_launch(void* const* d_in, const int* in_sizes, int n_in,
                              void* d_out, int out_size, void* d_ws, size_t ws_size,
                              hipStream_t stream) {
  (void)in_sizes; (void)n_in; (void)out_size; (void)ws_size;
  const float* x   = (const float*)d_in[0];
  const float* w1  = (const float*)d_in[1];
  const float* b1  = (const float*)d_in[2];
  const float* w2  = (const float*)d_in[3];
  const float* b2  = (const float*)d_in[4];
  const float* uw1 = (const float*)d_in[5];
  const float* ub1 = (const float*)d_in[6];
  const float* uw2 = (const float*)d_in[7];
  const float* ub2 = (const float*)d_in[8];
  float* out = (float*)d_out;
  char* ws = (char*)d_ws;

  // Live ranges: xnthl [0,8M) dead after k_sim2 -> topV/topI overlay (k_select writes).
  // sampV [21,54.5M) dead after k_theta -> U/T/V overlay (k_pre writes after k_select).
  // High-water 67 MB (< 68.3 proven in rounds 7/8).
  u16*   xnthl = (u16*)(ws + 0);                         // 8 MB (hi/lo granule-tiled xn)
  float* topV  = (float*)(ws + 0);                       // 1.31 MB (overlay, after k_sim2)
  int*   topI  = (int*)(ws + (2u << 20));                // 1.31 MB
  u16*   xbf   = (u16*)(ws + (8u << 20));                // 4 MB
  float* xnf   = (float*)(ws + (12u << 20));             // 8 MB
  u16*   wcatT = (u16*)(ws + (20u << 20));               // 96 KB
  u16*   w2T   = (u16*)(ws + (20u << 20) + 131072);      // 32 KB
  u16*   u1bT  = (u16*)(ws + (20u << 20) + 163840);      // 32 KB
  u16*   u2T   = (u16*)(ws + (20u << 20) + 196608);      // 32 KB
  int*   cnt   = (int*)(ws + (20u << 20) + 262144);      // 64 KB
  float* thbuf = (float*)(ws + (20u << 20) + 327680);    // 64 KB
  float* sampV = (float*)(ws + (21u << 20));             // 33.5 MB (transient)
  float* Uarr  = (float*)(ws + (21u << 20));             // 8 MB (overlay, after k_theta)
  float* Tarr  = (float*)(ws + (29u << 20));             // 8 MB
  float* Varr  = (float*)(ws + (37u << 20));             // 8 MB
  float* candV = (float*)(ws + (55u << 20));             // 6 MB
  int*   candI = (int*)(ws + (61u << 20));               // 6 MB

  hipLaunchKernelGGL(k_prep_w, dim3(384), dim3(256), 0, stream,
                     w1, w2, uw1, uw2, wcatT, w2T, u1bT, u2T);
  hipLaunchKernelGGL(k_norm, dim3(4096), dim3(256), 0, stream, x, xnf, xnthl, xbf, cnt);
  hipLaunchKernelGGL(k_sim1, dim3(1024), dim3(256), 0, stream, xnthl, sampV);
  hipLaunchKernelGGL(k_theta, dim3(4096), dim3(256), 0, stream, sampV, thbuf);
  hipLaunchKernelGGL(k_sim2, dim3(1024), dim3(256), 0, stream, xnthl, thbuf, candV, candI, cnt);
  hipLaunchKernelGGL(k_select, dim3(4096), dim3(256), 0, stream, xnf, candV, candI, cnt, topV, topI);
  hipLaunchKernelGGL(k_pre, dim3(256, 6), dim3(256), 0, stream, xbf, wcatT, Uarr, Tarr, Varr);
  hipLaunchKernelGGL(k_msg_upd, dim3(512), dim3(256), 0, stream,
                     x, Uarr, Tarr, Varr, topV, topI, b1, b2, ub1, ub2, w2T, u1bT, u2T, out);
}

// Round 10
// 348.704 us; speedup vs baseline: 1.1341x; 1.1341x over previous
//
#include <hip/hip_runtime.h>

typedef unsigned short u16;
typedef unsigned int u32;
typedef short vbf16x8 __attribute__((ext_vector_type(8)));   // 8 bf16 as shorts (4 VGPR)
typedef float vf32x4 __attribute__((ext_vector_type(4)));
typedef int vi32x4 __attribute__((ext_vector_type(4)));

#define MFMA16(a,b,c) __builtin_amdgcn_mfma_f32_16x16x32_bf16((a),(b),(c),0,0,0)

__device__ __forceinline__ u16 f2bf(float f) {
  union { float f; unsigned u; } c; c.f = f;
  unsigned r = c.u + 0x7fffu + ((c.u >> 16) & 1u);
  return (u16)(r >> 16);
}

// ---------------- prep: weight transposes (bf16) ----------------
__global__ __launch_bounds__(256) void k_prep_w(
    const float* __restrict__ w1, const float* __restrict__ w2,
    const float* __restrict__ u1, const float* __restrict__ u2,
    u16* __restrict__ wcatT, u16* __restrict__ w2T,
    u16* __restrict__ u1bT, u16* __restrict__ u2T) {
  int id = blockIdx.x * 256 + threadIdx.x;
  if (id < 49152) {
    int n = id >> 7, k = id & 127;
    float v;
    if (n < 128) v = w1[(128 + k) * 128 + n];
    else if (n < 256) v = w1[k * 128 + (n - 128)];
    else v = u1[k * 128 + (n - 256)];
    wcatT[id] = f2bf(v);
  } else {
    int id2 = id - 49152;
    int m = id2 >> 14, r = id2 & 16383;
    int n = r >> 7, k = r & 127;
    if (m == 0) w2T[r] = f2bf(w2[k * 128 + n]);
    else if (m == 1) u1bT[r] = f2bf(u1[(128 + k) * 128 + n]);
    else u2T[r] = f2bf(u2[k * 128 + n]);
  }
}

// ---------------- norms: xnf (f32), xbf (raw bf16), xnt (normalized bf16, MFMA-granule-tiled) --------
// xnt: granule (row j, ks, lg) at u16 offset (j>>4)*2048 + ks*512 + lg*128 + (j&15)*8.
__global__ __launch_bounds__(256) void k_norm(
    const float* __restrict__ x, float* __restrict__ xnf,
    u16* __restrict__ xnt, u16* __restrict__ xbf, int* __restrict__ cnt) {
  __shared__ u16 buf[4][128];
  int tid = threadIdx.x;
  int gid = blockIdx.x * 256 + tid;
  if (gid < 16384) cnt[gid] = 0;
  int lane = tid & 63, w = tid >> 6;
  int row = blockIdx.x * 4 + w;
  size_t b = (size_t)row * 128;
  float v0 = x[b + lane], v1 = x[b + 64 + lane];
  float ss = v0 * v0 + v1 * v1;
  #pragma unroll
  for (int m = 32; m > 0; m >>= 1) ss += __shfl_xor(ss, m);
  float d = fmaxf(sqrtf(ss), 1e-8f);
  float n0 = v0 / d, n1 = v1 / d;
  xnf[b + lane] = n0; xnf[b + 64 + lane] = n1;
  xbf[b + lane] = f2bf(v0); xbf[b + 64 + lane] = f2bf(v1);
  buf[w][lane] = f2bf(n0); buf[w][64 + lane] = f2bf(n1);
  __syncthreads();
  if (tid < 64) {
    int r = tid >> 4, g = tid & 15;
    int grow = blockIdx.x * 4 + r;
    vi32x4 d4 = *(const vi32x4*)&buf[r][g * 8];
    *(vi32x4*)&xnt[(size_t)(grow >> 4) * 2048 + (g >> 2) * 512 + (g & 3) * 128 + (grow & 15) * 8] = d4;
  }
}

// ---------------- sampling pass: per-(row,seg-stream) top-2 VALUES ---------------------------------
// Block: 256 rows (4 waves x 64 rows) x one 1024-col segment. Grid 1024. 3 VALU/value.
__global__ __launch_bounds__(256, 2) void k_sim1(
    const u16* __restrict__ xnt, float* __restrict__ sampV) {
  const int tid = threadIdx.x, lane = tid & 63, w = tid >> 6;
  const int lr = lane & 15, lg = lane >> 4;
  const int seg = blockIdx.x & 15, rbk = blockIdx.x >> 4;
  const int rowbase = rbk * 256 + w * 64;

  vbf16x8 af[4][4];
  #pragma unroll
  for (int a = 0; a < 4; ++a) {
    const u16* tp = xnt + (size_t)((rowbase >> 4) + a) * 2048;
    #pragma unroll
    for (int ks = 0; ks < 4; ++ks)
      af[a][ks] = *(const vbf16x8*)(tp + ks * 512 + lg * 128 + lr * 8);
  }

  float m1[4][4], m2[4][4];
  #pragma unroll
  for (int a = 0; a < 4; ++a)
    #pragma unroll
    for (int r = 0; r < 4; ++r) { m1[a][r] = -1e30f; m2[a][r] = -1e30f; }

  const u16* segp = xnt + (size_t)(seg * 64) * 2048;
  vbf16x8 bc[4], bn[4];
  #pragma unroll
  for (int ks = 0; ks < 4; ++ks) bc[ks] = *(const vbf16x8*)(segp + ks * 512 + lane * 8);

#define S1STEP(B) { \
  _Pragma("unroll") \
  for (int a = 0; a < 4; ++a) { \
    vf32x4 acc = {0.f, 0.f, 0.f, 0.f}; \
    _Pragma("unroll") \
    for (int ks = 0; ks < 4; ++ks) acc = MFMA16(af[a][ks], (B)[ks], acc); \
    _Pragma("unroll") \
    for (int r = 0; r < 4; ++r) { \
      float v = acc[r]; \
      m2[a][r] = fmaxf(m2[a][r], fminf(m1[a][r], v)); \
      m1[a][r] = fmaxf(m1[a][r], v); \
    } } }

  #pragma unroll 1
  for (int ti = 0; ti < 32; ++ti) {
    { const u16* tp1 = segp + (size_t)(2 * ti + 1) * 2048;
      #pragma unroll
      for (int ks = 0; ks < 4; ++ks) bn[ks] = *(const vbf16x8*)(tp1 + ks * 512 + lane * 8); }
    S1STEP(bc);
    { int nt = (ti < 31) ? (2 * ti + 2) : 63;
      const u16* tp2 = segp + (size_t)nt * 2048;
      #pragma unroll
      for (int ks = 0; ks < 4; ++ks) bc[ks] = *(const vbf16x8*)(tp2 + ks * 512 + lane * 8); }
    S1STEP(bn);
  }

  // dump 32 samples per (row, seg): sampV[row*512 + seg*32 + {lr, 16+lr}]
  #pragma unroll
  for (int a = 0; a < 4; ++a)
    #pragma unroll
    for (int r = 0; r < 4; ++r) {
      int row = rowbase + a * 16 + lg * 4 + r;
      float* dp = sampV + (size_t)row * 512 + seg * 32;
      dp[lr] = m1[a][r]; dp[16 + lr] = m2[a][r];
    }
}

// ---------------- theta: (28th-largest of 512-sample union) - 5e-3 --------------------------------
// s28 <= true28 <= true20 (v-space); -5e-3 = 2m margin (m=2.5e-3 ~ 9 sigma of bf16-dot noise)
// guarantees capture of every candidate with v >= mn - 2m, the set k_select's A/W/B logic needs.
__global__ __launch_bounds__(256) void k_theta(
    const float* __restrict__ sampV, float* __restrict__ thbuf) {
  const int lane = threadIdx.x & 63, w = threadIdx.x >> 6;
  const int row = blockIdx.x * 4 + w;
  const float* sp = sampV + (size_t)row * 512;
  float v[8];
  #pragma unroll
  for (int q = 0; q < 8; ++q) v[q] = sp[q * 64 + lane];
  float g = -1e30f;
  #pragma unroll 1
  for (int t = 0; t < 28; ++t) {
    float loc = v[0];
    #pragma unroll
    for (int q = 1; q < 8; ++q) loc = fmaxf(loc, v[q]);
    g = loc;
    #pragma unroll
    for (int mm = 1; mm < 64; mm <<= 1) g = fmaxf(g, __shfl_xor(g, mm));
    #pragma unroll
    for (int q = 0; q < 8; ++q) v[q] = (v[q] == g) ? -1e30f : v[q];
  }
  if (lane == 0) thbuf[row] = g - 5e-3f;
}

// ---------------- capture pass: bitwise-identical MFMAs, capture (v, col) >= theta(row) ------------
__global__ __launch_bounds__(256, 2) void k_sim2(
    const u16* __restrict__ xnt, const float* __restrict__ thbuf,
    float* __restrict__ candV, int* __restrict__ candI, int* __restrict__ cnt) {
  const int tid = threadIdx.x, lane = tid & 63, w = tid >> 6;
  const int lr = lane & 15, lg = lane >> 4;
  const int seg = blockIdx.x & 15, rbk = blockIdx.x >> 4;
  const int rowbase = rbk * 256 + w * 64;

  vbf16x8 af[4][4];
  #pragma unroll
  for (int a = 0; a < 4; ++a) {
    const u16* tp = xnt + (size_t)((rowbase >> 4) + a) * 2048;
    #pragma unroll
    for (int ks = 0; ks < 4; ++ks)
      af[a][ks] = *(const vbf16x8*)(tp + ks * 512 + lg * 128 + lr * 8);
  }
  float th[4][4];
  #pragma unroll
  for (int a = 0; a < 4; ++a)
    #pragma unroll
    for (int r = 0; r < 4; ++r) th[a][r] = thbuf[rowbase + a * 16 + lg * 4 + r];

  const u16* segp = xnt + (size_t)(seg * 64) * 2048;
  vbf16x8 bc[4], bn[4];
  #pragma unroll
  for (int ks = 0; ks < 4; ++ks) bc[ks] = *(const vbf16x8*)(segp + ks * 512 + lane * 8);

#define S2STEP(B, COLB) { \
  _Pragma("unroll") \
  for (int a = 0; a < 4; ++a) { \
    vf32x4 acc = {0.f, 0.f, 0.f, 0.f}; \
    _Pragma("unroll") \
    for (int ks = 0; ks < 4; ++ks) acc = MFMA16(af[a][ks], (B)[ks], acc); \
    _Pragma("unroll") \
    for (int r = 0; r < 4; ++r) { \
      float v = acc[r]; \
      if (v >= th[a][r]) { \
        int row = rowbase + a * 16 + lg * 4 + r; \
        int s = atomicAdd(&cnt[row], 1); \
        if (s < 96) { candV[(size_t)row * 96 + s] = v; candI[(size_t)row * 96 + s] = (COLB) + lr; } \
      } } } }

  const int colseg = seg * 1024;
  #pragma unroll 1
  for (int ti = 0; ti < 32; ++ti) {
    { const u16* tp1 = segp + (size_t)(2 * ti + 1) * 2048;
      #pragma unroll
      for (int ks = 0; ks < 4; ++ks) bn[ks] = *(const vbf16x8*)(tp1 + ks * 512 + lane * 8); }
    S2STEP(bc, colseg + (2 * ti) * 16);
    { int nt = (ti < 31) ? (2 * ti + 2) : 63;
      const u16* tp2 = segp + (size_t)nt * 2048;
      #pragma unroll
      for (int ks = 0; ks < 4; ++ks) bc[ks] = *(const vbf16x8*)(tp2 + ks * 512 + lane * 8); }
    S2STEP(bn, colseg + (2 * ti + 1) * 16);
  }
}

// ---------------- select: rank by v; A auto-in, B out, window W exact-rescored ---------------------
// m = 2.5e-3 bounds |v - fp32|. mn = 20th v. A = {v > mn+2m} provably in fp32-top-20;
// {v < mn-2m} provably out; W = [mn-2m, mn+2m] rescored exactly (E|W|~10), fills 20-|A| slots.
__global__ __launch_bounds__(256) void k_select(
    const float* __restrict__ xnf,
    const float* __restrict__ candV, const int* __restrict__ candI, const int* __restrict__ cnt,
    float* __restrict__ topV, int* __restrict__ topI) {
  __shared__ float svals[4][96];
  __shared__ int   sidx[4][96];
  __shared__ int   wlist[4][32];
  __shared__ float wex[4][32];
  const int tid = threadIdx.x, lane = tid & 63, w = tid >> 6;
  const int i = blockIdx.x * 4 + w;
  int c = cnt[i]; if (c > 96) c = 96;
  float v0 = -1e30f, v1 = -1e30f; int i0 = 0x7fffffff, i1 = 0x7fffffff;
  const int s1i = 64 + lane;
  if (lane < c) { v0 = candV[(size_t)i * 96 + lane]; i0 = candI[(size_t)i * 96 + lane];
                  svals[w][lane] = v0; sidx[w][lane] = i0; }
  if (s1i < c)  { v1 = candV[(size_t)i * 96 + s1i]; i1 = candI[(size_t)i * 96 + s1i];
                  svals[w][s1i] = v1; sidx[w][s1i] = i1; }
  __syncthreads();
  int r0 = 0, r1 = 0;
  #pragma unroll 1
  for (int s = 0; s < c; ++s) {
    float vs = svals[w][s]; int is = sidx[w][s];
    r0 += (vs > v0 || (vs == v0 && is < i0)) ? 1 : 0;
    r1 += (vs > v1 || (vs == v1 && is < i1)) ? 1 : 0;
  }
  bool ok0 = lane < c, ok1 = s1i < c;
  bool win0 = ok0 && r0 < 20, win1 = ok1 && r1 < 20;
  float mn = 1e30f;
  if (win0) mn = v0;
  if (win1) mn = fminf(mn, v1);
  #pragma unroll
  for (int m = 1; m < 64; m <<= 1) mn = fminf(mn, __shfl_xor(mn, m));
  const float M2 = 5e-3f;   // 2m
  bool isA0 = ok0 && v0 > mn + M2;
  bool isA1 = ok1 && v1 > mn + M2;
  bool isW0 = ok0 && fabsf(v0 - mn) <= M2;
  bool isW1 = ok1 && fabsf(v1 - mn) <= M2;
  int nA = __popcll(__ballot(isA0)) + __popcll(__ballot(isA1));
  unsigned long long bw0 = __ballot(isW0), bw1 = __ballot(isW1);
  int nW0 = __popcll(bw0);
  int nW = nW0 + __popcll(bw1);
  int wp0 = 99, wp1 = 99;
  if (isW0) { wp0 = __popcll(bw0 & ((1ull << lane) - 1ull)); if (wp0 < 32) wlist[w][wp0] = i0; }
  if (isW1) { wp1 = nW0 + __popcll(bw1 & ((1ull << lane) - 1ull)); if (wp1 < 32) wlist[w][wp1] = i1; }
  if (nW > 32) nW = 32;
  __syncthreads();
  { // parallel exact rescore: 8 groups x 8 lanes, 16 channels/lane
    const int g = lane >> 3, sl = lane & 7;
    const float* xip = &xnf[(size_t)i * 128 + sl * 16];
    vf32x4 xi0 = *(const vf32x4*)&xip[0];
    vf32x4 xi1 = *(const vf32x4*)&xip[4];
    vf32x4 xi2 = *(const vf32x4*)&xip[8];
    vf32x4 xi3 = *(const vf32x4*)&xip[12];
    #pragma unroll 1
    for (int t = g; t < nW; t += 8) {
      int j = wlist[w][t];
      const float* xjp = &xnf[(size_t)j * 128 + sl * 16];
      vf32x4 a0 = *(const vf32x4*)&xjp[0];
      vf32x4 a1 = *(const vf32x4*)&xjp[4];
      vf32x4 a2 = *(const vf32x4*)&xjp[8];
      vf32x4 a3 = *(const vf32x4*)&xjp[12];
      float p = xi0[0]*a0[0] + xi0[1]*a0[1] + xi0[2]*a0[2] + xi0[3]*a0[3]
              + xi1[0]*a1[0] + xi1[1]*a1[1] + xi1[2]*a1[2] + xi1[3]*a1[3]
              + xi2[0]*a2[0] + xi2[1]*a2[1] + xi2[2]*a2[2] + xi2[3]*a2[3]
              + xi3[0]*a3[0] + xi3[1]*a3[1] + xi3[2]*a3[2] + xi3[3]*a3[3];
      p += __shfl_xor(p, 1); p += __shfl_xor(p, 2); p += __shfl_xor(p, 4);
      if (sl == 0) wex[w][t] = p;
    }
  }
  __syncthreads();
  float e0 = -1e30f, e1 = -1e30f;
  if (isW0 && wp0 < 32) e0 = wex[w][wp0];
  if (isW1 && wp1 < 32) e1 = wex[w][wp1];
  int rw0 = 0, rw1 = 0;
  #pragma unroll 1
  for (int t = 0; t < nW; ++t) {
    float et = wex[w][t]; int jt = wlist[w][t];
    rw0 += (et > e0 || (et == e0 && jt < i0)) ? 1 : 0;
    rw1 += (et > e1 || (et == e1 && jt < i1)) ? 1 : 0;
  }
  const int need = 20 - nA;
  bool fw0 = isW0 && (wp0 < 32) && rw0 < need;
  bool fw1 = isW1 && (wp1 < 32) && rw1 < need;
  bool final0 = isA0 || fw0;
  bool final1 = isA1 || fw1;
  float o0 = isA0 ? v0 : e0;
  float o1 = isA1 ? v1 : e1;
  unsigned long long b0 = __ballot(final0);
  if (final0) {
    int pos = __popcll(b0 & ((1ull << lane) - 1ull));
    topV[(size_t)i * 20 + pos] = o0; topI[(size_t)i * 20 + pos] = i0;
  }
  int bse = __popcll(b0);
  unsigned long long b1 = __ballot(final1);
  if (final1) {
    int pos = bse + __popcll(b1 & ((1ull << lane) - 1ull));
    topV[(size_t)i * 20 + pos] = o1; topI[(size_t)i * 20 + pos] = i1;
  }
}

// ---------------- precompute U = x@w1[128:], T = x@w1[:128], V = x@uw1[:128] ----------------
__global__ __launch_bounds__(256) void k_pre(
    const u16* __restrict__ xbf, const u16* __restrict__ wcatT,
    float* __restrict__ U, float* __restrict__ T, float* __restrict__ V) {
  const int tid = threadIdx.x, lane = tid & 63, w = tid >> 6;
  const int lr = lane & 15, lg = lane >> 4;
  const int rowbase = blockIdx.x * 64, cb = blockIdx.y;
  const int a = w >> 1, b = w & 1;
  vbf16x8 af[2][4];
  #pragma unroll
  for (int ar = 0; ar < 2; ++ar) {
    const u16* rp = xbf + (size_t)(rowbase + (a * 2 + ar) * 16 + lr) * 128;
    #pragma unroll
    for (int ks = 0; ks < 4; ++ks) af[ar][ks] = *(const vbf16x8*)(rp + ks * 32 + lg * 8);
  }
  vf32x4 z = {0.f, 0.f, 0.f, 0.f};
  vf32x4 acc[2][2] = {{z, z}, {z, z}};
  #pragma unroll
  for (int ks = 0; ks < 4; ++ks) {
    vbf16x8 bf[2];
    #pragma unroll
    for (int cbl = 0; cbl < 2; ++cbl) {
      int gcol = cb * 64 + (b * 2 + cbl) * 16 + lr;
      bf[cbl] = *(const vbf16x8*)(wcatT + (size_t)gcol * 128 + ks * 32 + lg * 8);
    }
    #pragma unroll
    for (int ar = 0; ar < 2; ++ar)
      #pragma unroll
      for (int cbl = 0; cbl < 2; ++cbl)
        acc[ar][cbl] = MFMA16(af[ar][ks], bf[cbl], acc[ar][cbl]);
  }
  #pragma unroll
  for (int ar = 0; ar < 2; ++ar)
    #pragma unroll
    for (int cbl = 0; cbl < 2; ++cbl) {
      int gcol = cb * 64 + (b * 2 + cbl) * 16 + lr;
      #pragma unroll
      for (int r = 0; r < 4; ++r) {
        int grow = rowbase + (a * 2 + ar) * 16 + lg * 4 + r;
        float vv = acc[ar][cbl][r];
        if (gcol < 128)      U[(size_t)grow * 128 + gcol] = vv;
        else if (gcol < 256) T[(size_t)grow * 128 + (gcol - 128)] = vv;
        else                 V[(size_t)grow * 128 + (gcol - 256)] = vv;
      }
    }
}

// ---------------- fused: softmax, G = sum_e s_e*relu(T_i+U_j+b1), h_agg, update MLP ----------------
__global__ __launch_bounds__(256) void k_msg_upd(
    const float* __restrict__ x,
    const float* __restrict__ Uarr, const float* __restrict__ Tarr, const float* __restrict__ Varr,
    const float* __restrict__ topV, const int* __restrict__ topI,
    const float* __restrict__ b1, const float* __restrict__ b2,
    const float* __restrict__ ub1, const float* __restrict__ ub2,
    const u16* __restrict__ w2T, const u16* __restrict__ u1bT, const u16* __restrict__ u2T,
    float* __restrict__ out) {
  __shared__ float wsm[32 * 20];
  __shared__ int   ism[32 * 20];
  __shared__ u16   Gbf[32 * 136];
  __shared__ u16   Hbf[32 * 136];
  const int tid = threadIdx.x, lane = tid & 63, w = tid >> 6;
  const int lr = lane & 15, lg = lane >> 4;
  const int base = blockIdx.x * 32;

  if (tid < 32) { // softmax over top-20 sims (order-independent)
    int i = base + tid;
    float vv[20]; float mx = -1e30f;
    #pragma unroll
    for (int e = 0; e < 20; ++e) { vv[e] = topV[(size_t)i * 20 + e]; mx = fmaxf(mx, vv[e]); }
    float s = 0.f;
    #pragma unroll
    for (int e = 0; e < 20; ++e) { vv[e] = __expf(vv[e] - mx); s += vv[e]; }
    float inv = 1.f / s;
    #pragma unroll
    for (int e = 0; e < 20; ++e) {
      wsm[tid * 20 + e] = vv[e] * inv;
      ism[tid * 20 + e] = topI[(size_t)i * 20 + e];
    }
  }
  __syncthreads();

  { // G step: 8 threads per row, 16 channels each
    int r = tid >> 3, q = tid & 7, ch0 = q * 16;
    int i = base + r;
    vf32x4 z = {0.f, 0.f, 0.f, 0.f};
    vf32x4 tr[4], br[4], acc[4];
    #pragma unroll
    for (int c = 0; c < 4; ++c) {
      tr[c] = *(const vf32x4*)&Tarr[(size_t)i * 128 + ch0 + c * 4];
      br[c] = *(const vf32x4*)&b1[ch0 + c * 4];
      acc[c] = z;
    }
    #pragma unroll 1
    for (int e = 0; e < 20; ++e) {
      int j = ism[r * 20 + e]; float s = wsm[r * 20 + e];
      const vf32x4* up = (const vf32x4*)&Uarr[(size_t)j * 128 + ch0];
      #pragma unroll
      for (int c = 0; c < 4; ++c) {
        vf32x4 u = up[c];
        #pragma unroll
        for (int zz = 0; zz < 4; ++zz) {
          float p = tr[c][zz] + u[zz] + br[c][zz];
          acc[c][zz] += s * fmaxf(p, 0.f);
        }
      }
    }
    #pragma unroll
    for (int c = 0; c < 4; ++c)
      #pragma unroll
      for (int zz = 0; zz < 4; ++zz)
        Gbf[r * 136 + ch0 + c * 4 + zz] = f2bf(acc[c][zz]);
  }
  __syncthreads();

  const int rt = w >> 1, cg = w & 1;
  vf32x4 z4 = {0.f, 0.f, 0.f, 0.f};
  { // GEMM1: h_agg = G @ w2 + b2 -> Hbf
    vf32x4 acc[4] = {z4, z4, z4, z4};
    #pragma unroll
    for (int ks = 0; ks < 4; ++ks) {
      vbf16x8 a = *(const vbf16x8*)&Gbf[(rt * 16 + lr) * 136 + ks * 32 + lg * 8];
      #pragma unroll
      for (int c = 0; c < 4; ++c) {
        int col = (cg * 4 + c) * 16 + lr;
        vbf16x8 bb = *(const vbf16x8*)(w2T + (size_t)col * 128 + ks * 32 + lg * 8);
        acc[c] = MFMA16(a, bb, acc[c]);
      }
    }
    #pragma unroll
    for (int c = 0; c < 4; ++c) {
      int col = (cg * 4 + c) * 16 + lr;
      float bias = b2[col];
      #pragma unroll
      for (int r = 0; r < 4; ++r) {
        int row = rt * 16 + lg * 4 + r;
        Hbf[row * 136 + col] = f2bf(acc[c][r] + bias);
      }
    }
  }
  __syncthreads();
  { // GEMM2: pre = h_agg @ uw1[128:] + V_i + ub1, relu -> Gbf (reused as P)
    vf32x4 acc[4] = {z4, z4, z4, z4};
    #pragma unroll
    for (int ks = 0; ks < 4; ++ks) {
      vbf16x8 a = *(const vbf16x8*)&Hbf[(rt * 16 + lr) * 136 + ks * 32 + lg * 8];
      #pragma unroll
      for (int c = 0; c < 4; ++c) {
        int col = (cg * 4 + c) * 16 + lr;
        vbf16x8 bb = *(const vbf16x8*)(u1bT + (size_t)col * 128 + ks * 32 + lg * 8);
        acc[c] = MFMA16(a, bb, acc[c]);
      }
    }
    #pragma unroll
    for (int c = 0; c < 4; ++c) {
      int col = (cg * 4 + c) * 16 + lr;
      float bias = ub1[col];
      #pragma unroll
      for (int r = 0; r < 4; ++r) {
        int row = rt * 16 + lg * 4 + r;
        float vv = acc[c][r] + Varr[(size_t)(base + row) * 128 + col] + bias;
        Gbf[row * 136 + col] = f2bf(fmaxf(vv, 0.f));
      }
    }
  }
  __syncthreads();
  { // GEMM3: out = x + P @ uw2 + ub2
    vf32x4 acc[4] = {z4, z4, z4, z4};
    #pragma unroll
    for (int ks = 0; ks < 4; ++ks) {
      vbf16x8 a = *(const vbf16x8*)&Gbf[(rt * 16 + lr) * 136 + ks * 32 + lg * 8];
      #pragma unroll
      for (int c = 0; c < 4; ++c) {
        int col = (cg * 4 + c) * 16 + lr;
        vbf16x8 bb = *(const vbf16x8*)(u2T + (size_t)col * 128 + ks * 32 + lg * 8);
        acc[c] = MFMA16(a, bb, acc[c]);
      }
    }
    #pragma unroll
    for (int c = 0; c < 4; ++c) {
      int col = (cg * 4 + c) * 16 + lr;
      float bias = ub2[col];
      #pragma unroll
      for (int r = 0; r < 4; ++r) {
        int row = rt * 16 + lg * 4 + r;
        size_t o = (size_t)(base + row) * 128 + col;
        out[o] = x[o] + acc[c][r] + bias;
      }
    }
  }
}

extern "C" void kernel_launch(void* const* d_in, const int* in_sizes, int n_in,
                              void* d_out, int out_size, void* d_ws, size_t ws_size,
                              hipStream_t stream) {
  (void)in_sizes; (void)n_in; (void)out_size; (void)ws_size;
  const float* x   = (const float*)d_in[0];
  const float* w1  = (const float*)d_in[1];
  const float* b1  = (const float*)d_in[2];
  const float* w2  = (const float*)d_in[3];
  const float* b2  = (const float*)d_in[4];
  const float* uw1 = (const float*)d_in[5];
  const float* ub1 = (const float*)d_in[6];
  const float* uw2 = (const float*)d_in[7];
  const float* ub2 = (const float*)d_in[8];
  float* out = (float*)d_out;
  char* ws = (char*)d_ws;

  // Live ranges: sampV [17,50.6M) dies after k_theta; U/T/V [17,41) overlay it (k_pre runs after
  // k_select). candV/candI/topV/topI in [51,68.31M) - high-water 68.31 MB (= rounds 7/8, proven).
  u16*   xnt   = (u16*)(ws + 0);                         // 4 MB (granule-tiled xn bf16)
  u16*   xbf   = (u16*)(ws + (4u << 20));                // 4 MB
  float* xnf   = (float*)(ws + (8u << 20));              // 8 MB
  u16*   wcatT = (u16*)(ws + (16u << 20));               // 96 KB
  u16*   w2T   = (u16*)(ws + (16u << 20) + 131072);      // 32 KB
  u16*   u1bT  = (u16*)(ws + (16u << 20) + 163840);      // 32 KB
  u16*   u2T   = (u16*)(ws + (16u << 20) + 196608);      // 32 KB
  int*   cnt   = (int*)(ws + (16u << 20) + 262144);      // 64 KB
  float* thbuf = (float*)(ws + (16u << 20) + 327680);    // 64 KB
  float* sampV = (float*)(ws + (17u << 20));             // 33.5 MB (transient)
  float* Uarr  = (float*)(ws + (17u << 20));             // 8 MB (overlay, after k_theta)
  float* Tarr  = (float*)(ws + (25u << 20));             // 8 MB
  float* Varr  = (float*)(ws + (33u << 20));             // 8 MB
  float* candV = (float*)(ws + (51u << 20));             // 6.3 MB
  int*   candI = (int*)(ws + (58u << 20));               // 6.3 MB
  float* topV  = (float*)(ws + (65u << 20));             // 1.31 MB
  int*   topI  = (int*)(ws + (67u << 20));               // 1.31 MB

  hipLaunchKernelGGL(k_prep_w, dim3(384), dim3(256), 0, stream,
                     w1, w2, uw1, uw2, wcatT, w2T, u1bT, u2T);
  hipLaunchKernelGGL(k_norm, dim3(4096), dim3(256), 0, stream, x, xnf, xnt, xbf, cnt);
  hipLaunchKernelGGL(k_sim1, dim3(1024), dim3(256), 0, stream, xnt, sampV);
  hipLaunchKernelGGL(k_theta, dim3(4096), dim3(256), 0, stream, sampV, thbuf);
  hipLaunchKernelGGL(k_sim2, dim3(1024), dim3(256), 0, stream, xnt, thbuf, candV, candI, cnt);
  hipLaunchKernelGGL(k_select, dim3(4096), dim3(256), 0, stream, xnf, candV, candI, cnt, topV, topI);
  hipLaunchKernelGGL(k_pre, dim3(256, 6), dim3(256), 0, stream, xbf, wcatT, Uarr, Tarr, Varr);
  hipLaunchKernelGGL(k_msg_upd, dim3(512), dim3(256), 0, stream,
                     x, Uarr, Tarr, Varr, topV, topI, b1, b2, ub1, ub2, w2T, u1bT, u2T, out);
}